// Round 1
// baseline (711.555 us; speedup 1.0000x reference)
//
#include <hip/hip_runtime.h>
#include <stdint.h>

#define H_ 16
#define DH_ 128
#define RK_ 512
#define RD_ 64
#define B_ 2
#define L_ 2048
#define E_ 2048
#define DQ_ 192            // DH+RD
#define NQ_ (H_*DQ_)       // 3072
#define NKV_ 576
#define NKVP_ 640
#define NUP_ (H_*(2*DH_+RD_)) // 5120
#define M_ (B_*L_)         // 4096

typedef unsigned short u16;
typedef __bf16 bf16x8 __attribute__((ext_vector_type(8)));
typedef float floatx4 __attribute__((ext_vector_type(4)));

__device__ __forceinline__ u16 f2bf(float f) {
    union { float f; uint32_t u; } v; v.f = f;
    uint32_t u = v.u;
    u = (u + 0x7fffu + ((u >> 16) & 1u)) >> 16;
    return (u16)u;
}

__device__ __forceinline__ void gld_lds16(const void* g, void* l) {
    __builtin_amdgcn_global_load_lds((__attribute__((address_space(1))) void*)(g),
                                     (__attribute__((address_space(3))) void*)(l),
                                     16, 0, 0);
}

// ---------------- fp32 -> bf16 elementwise (x) ----------------
__global__ void convert_bf16(const float* __restrict__ in, u16* __restrict__ out, int n4) {
    int i = blockIdx.x * blockDim.x + threadIdx.x;
    if (i >= n4) return;
    float4 v = ((const float4*)in)[i];
    uint2 o;
    o.x = (uint32_t)f2bf(v.x) | ((uint32_t)f2bf(v.y) << 16);
    o.y = (uint32_t)f2bf(v.z) | ((uint32_t)f2bf(v.w) << 16);
    ((uint2*)out)[i] = o;
}

// ---------------- W (KxN fp32) -> Wt (Npad x K bf16), zero pad ----------------
__global__ void transpose_w(const float* __restrict__ W, u16* __restrict__ Wt,
                            int K, int N, int Npad) {
    __shared__ float tile[32][33];
    int n0 = blockIdx.x * 32, k0 = blockIdx.y * 32;
    int tx = threadIdx.x, ty = threadIdx.y; // 32 x 8
    for (int i = 0; i < 4; i++) {
        int k = k0 + ty + i * 8, n = n0 + tx;
        tile[ty + i * 8][tx] = (n < N) ? W[(size_t)k * N + n] : 0.f;
    }
    __syncthreads();
    for (int i = 0; i < 4; i++) {
        int n = n0 + ty + i * 8, k = k0 + tx;
        Wt[(size_t)n * K + k] = f2bf(tile[tx][ty + i * 8]);
    }
}

// ---------------- GEMM: C(MxN fp32) = A(MxK bf16) * Bt(NxK bf16)^T ----------------
// tiles 128x128x32, 256 threads = 4 waves (2x2 of 64x64), 16x16x32 MFMA
__global__ __launch_bounds__(256) void gemm_bt(const u16* __restrict__ A,
                                               const u16* __restrict__ Bt,
                                               float* __restrict__ C,
                                               int M, int N, int K) {
    __shared__ __align__(16) u16 As[128 * 32];
    __shared__ __align__(16) u16 Bs[128 * 32];
    const int tid = threadIdx.x;
    const int wave = tid >> 6, lane = tid & 63;
    const int quad = lane >> 4, l16 = lane & 15;
    const int m0 = blockIdx.y * 128, n0 = blockIdx.x * 128;
    const int wm = (wave >> 1) * 64, wn = (wave & 1) * 64;

    floatx4 zero4 = {0.f, 0.f, 0.f, 0.f};
    floatx4 acc[4][4];
    for (int i = 0; i < 4; i++) for (int j = 0; j < 4; j++) acc[i][j] = zero4;

    const u16* Ab = A + (size_t)m0 * K;
    const u16* Bb = Bt + (size_t)n0 * K;

    for (int k0 = 0; k0 < K; k0 += 32) {
        for (int it = 0; it < 2; ++it) {
            int c = it * 256 + tid;
            int row = c >> 2, cr = c & 3;
            gld_lds16(Ab + (size_t)row * K + k0 + cr * 8, As + c * 8);
            gld_lds16(Bb + (size_t)row * K + k0 + cr * 8, Bs + c * 8);
        }
        __syncthreads();
        bf16x8 af[4], bfr[4];
        for (int i = 0; i < 4; i++) af[i]  = *(const bf16x8*)(As + (wm + i * 16 + l16) * 32 + quad * 8);
        for (int j = 0; j < 4; j++) bfr[j] = *(const bf16x8*)(Bs + (wn + j * 16 + l16) * 32 + quad * 8);
        for (int i = 0; i < 4; i++)
            for (int j = 0; j < 4; j++)
                acc[i][j] = __builtin_amdgcn_mfma_f32_16x16x32_bf16(af[i], bfr[j], acc[i][j], 0, 0, 0);
        __syncthreads();
    }
    for (int i = 0; i < 4; i++)
        for (int j = 0; j < 4; j++) {
            int mrow = m0 + wm + i * 16 + quad * 4;
            int ncol = n0 + wn + j * 16 + l16;
            float* Cp = C + (size_t)mrow * N + ncol;
            for (int r = 0; r < 4; r++) Cp[(size_t)r * N] = acc[i][j][r];
        }
}

// ---------------- build q: rope + layout (B,H,L,192) bf16 ----------------
__global__ void build_q(const float* __restrict__ q_all, const float* __restrict__ cosT,
                        const float* __restrict__ sinT, u16* __restrict__ qb) {
    int idx = blockIdx.x * blockDim.x + threadIdx.x;
    if (idx >= M_ * H_ * 96) return;
    int p = idx % 96; int t = idx / 96; int h = t % H_; int row = t / H_;
    int l = row & (L_ - 1); int b = row >> 11;
    const float* src = q_all + (size_t)row * NQ_ + h * DQ_;
    u16* dst = qb + ((size_t)(b * H_ + h) * L_ + l) * DQ_;
    int d = 2 * p;
    float x1 = src[d], x2 = src[d + 1];
    if (d < DH_) { dst[d] = f2bf(x1); dst[d + 1] = f2bf(x2); }
    else {
        int i = (d - DH_) >> 1;
        float c = cosT[(size_t)l * 32 + i], s = sinT[(size_t)l * 32 + i];
        dst[d]     = f2bf(x1 * c - x2 * s);
        dst[d + 1] = f2bf(x1 * s + x2 * c);
    }
}

// ---------------- build c_kv (bf16) + roped k_rope (bf16) ----------------
__global__ void build_ckv(const float* __restrict__ kv, const float* __restrict__ cosT,
                          const float* __restrict__ sinT, u16* __restrict__ ckv,
                          u16* __restrict__ kropeb) {
    int idx = blockIdx.x * blockDim.x + threadIdx.x;
    if (idx >= M_ * 288) return;
    int j = idx % 288; int row = idx / 288;
    int l = row & (L_ - 1);
    const float* src = kv + (size_t)row * NKVP_;
    if (j < 256) {
        ckv[(size_t)row * RK_ + 2 * j]     = f2bf(src[2 * j]);
        ckv[(size_t)row * RK_ + 2 * j + 1] = f2bf(src[2 * j + 1]);
    } else {
        int i = j - 256;
        float x1 = src[RK_ + 2 * i], x2 = src[RK_ + 2 * i + 1];
        float c = cosT[(size_t)l * 32 + i], s = sinT[(size_t)l * 32 + i];
        kropeb[(size_t)row * RD_ + 2 * i]     = f2bf(x1 * c - x2 * s);
        kropeb[(size_t)row * RD_ + 2 * i + 1] = f2bf(x1 * s + x2 * c);
    }
}

// ---------------- build k (B,H,L,192) + vT (B,H,192,L), bf16 ----------------
__global__ __launch_bounds__(256) void build_kvt(const float* __restrict__ up,
        const u16* __restrict__ kropeb, u16* __restrict__ kb, u16* __restrict__ vtb) {
    __shared__ float vt[64][193];
    int blk = blockIdx.x;          // (b*H+h)*32 + lt
    int lt = blk & 31; int bh = blk >> 5; int h = bh % H_; int b = bh / H_;
    int tid = threadIdx.x;
    int l0 = lt * 64;
    for (int it = 0; it < 48; ++it) {
        int idx = it * 256 + tid;  // 64*192
        int lr = idx / 192, d = idx % 192;
        size_t row = (size_t)b * L_ + l0 + lr;
        float vv = (d < DH_) ? up[row * NUP_ + h * 320 + DH_ + d]
                             : up[row * NUP_ + h * 320 + 2 * DH_ + (d - DH_)];
        vt[lr][d] = vv;
        u16 kbf = (d < DH_) ? f2bf(up[row * NUP_ + h * 320 + d])
                            : kropeb[row * RD_ + (d - DH_)];
        kb[((size_t)bh * L_ + l0 + lr) * DQ_ + d] = kbf;
    }
    __syncthreads();
    for (int it = 0; it < 48; ++it) {
        int idx = it * 256 + tid;
        int lr = idx & 63, d = idx >> 6;
        vtb[((size_t)bh * DQ_ + d) * L_ + l0 + lr] = f2bf(vt[lr][d]);
    }
}

// ---------------- flash attention, causal ----------------
// qb,kb: (B*H, L, 192) bf16; vtb: (B*H, 192, L) bf16; ao: (B, L, H, 192) bf16
// LDS K: 6 panels [kk][64][32]; V: 2 panels [kk2][192][32]; P per wave: [kk2][16][32]
__global__ __launch_bounds__(256) void attn(const u16* __restrict__ qb,
        const u16* __restrict__ kb, const u16* __restrict__ vtb, u16* __restrict__ ao) {
    __shared__ __align__(16) u16 Ks[6 * 64 * 32];
    __shared__ __align__(16) u16 Vs[2 * 192 * 32];
    __shared__ __align__(16) u16 Ps[4][2 * 16 * 32];
    int qt = blockIdx.x, bh = blockIdx.y;
    int tid = threadIdx.x, wave = tid >> 6, lane = tid & 63;
    int quad = lane >> 4, l16 = lane & 15;
    const float scale = 0.07216878364870323f; // 1/sqrt(192)

    bf16x8 aq[6];
    const u16* qbase = qb + ((size_t)bh * L_ + qt * 64 + wave * 16 + l16) * DQ_;
    for (int kk = 0; kk < 6; kk++) aq[kk] = *(const bf16x8*)(qbase + kk * 32 + quad * 8);

    floatx4 zero4 = {0.f, 0.f, 0.f, 0.f};
    floatx4 o[12];
    for (int i = 0; i < 12; i++) o[i] = zero4;
    float m_i[4], l_i[4];
    for (int r = 0; r < 4; r++) { m_i[r] = -INFINITY; l_i[r] = 0.f; }

    const u16* kbase0 = kb + (size_t)bh * L_ * DQ_;
    const u16* vbase0 = vtb + (size_t)bh * DQ_ * L_;
    int qrow_base = qt * 64 + wave * 16 + quad * 4;

    for (int st = 0; st <= qt; ++st) {
        // stage K: panel kk=it, lane c covers row s=tid>>2, chunk q=tid&3
        const u16* kg = kbase0 + (size_t)st * 64 * DQ_;
        for (int it = 0; it < 6; ++it) {
            int c = it * 256 + tid;
            int s = tid >> 2, q = tid & 3;
            gld_lds16(kg + (size_t)s * DQ_ + it * 32 + q * 8, Ks + c * 8);
        }
        // stage V: panels kk2 = (c>=768); within panel d=cc>>2, chunk q=cc&3
        for (int it = 0; it < 6; ++it) {
            int c = it * 256 + tid;
            int kk2 = (c >= 768) ? 1 : 0;
            int cc = c - kk2 * 768;
            int d = cc >> 2, q = cc & 3;
            gld_lds16(vbase0 + (size_t)d * L_ + st * 64 + kk2 * 32 + q * 8, Vs + c * 8);
        }
        __syncthreads();

        // S = Q K^T
        float p[4][4];
        float mx[4];
        for (int r = 0; r < 4; r++) mx[r] = -INFINITY;
        for (int n = 0; n < 4; n++) {
            floatx4 sacc = zero4;
            for (int kk = 0; kk < 6; kk++) {
                bf16x8 bk = *(const bf16x8*)(Ks + kk * 2048 + (n * 16 + l16) * 32 + quad * 8);
                sacc = __builtin_amdgcn_mfma_f32_16x16x32_bf16(aq[kk], bk, sacc, 0, 0, 0);
            }
            int scol = st * 64 + n * 16 + l16;
            for (int r = 0; r < 4; r++) {
                float v = sacc[r] * scale;
                if (scol > qrow_base + r) v = -1e30f;
                p[n][r] = v;
                mx[r] = fmaxf(mx[r], v);
            }
        }
        for (int r = 0; r < 4; r++) {
            float m = mx[r];
            m = fmaxf(m, __shfl_xor(m, 1));
            m = fmaxf(m, __shfl_xor(m, 2));
            m = fmaxf(m, __shfl_xor(m, 4));
            m = fmaxf(m, __shfl_xor(m, 8));
            mx[r] = m;
        }
        float alpha[4];
        for (int r = 0; r < 4; r++) {
            float mn = fmaxf(m_i[r], mx[r]);
            alpha[r] = __expf(m_i[r] - mn);
            m_i[r] = mn;
        }
        float rs[4] = {0.f, 0.f, 0.f, 0.f};
        for (int n = 0; n < 4; n++)
            for (int r = 0; r < 4; r++) {
                float e = __expf(p[n][r] - m_i[r]);
                p[n][r] = e;
                rs[r] += e;
            }
        for (int r = 0; r < 4; r++) {
            float s = rs[r];
            s += __shfl_xor(s, 1); s += __shfl_xor(s, 2);
            s += __shfl_xor(s, 4); s += __shfl_xor(s, 8);
            l_i[r] = l_i[r] * alpha[r] + s;
        }
        for (int i = 0; i < 12; i++)
            for (int r = 0; r < 4; r++) o[i][r] *= alpha[r];

        // P -> LDS (panelized [kk2][16][32]), then PV
        u16* pw = &Ps[wave][0];
        for (int n = 0; n < 4; n++)
            for (int r = 0; r < 4; r++)
                pw[(n >> 1) * 512 + (quad * 4 + r) * 32 + (n & 1) * 16 + l16] = f2bf(p[n][r]);

        bf16x8 ap0 = *(const bf16x8*)(pw + l16 * 32 + quad * 8);
        bf16x8 ap1 = *(const bf16x8*)(pw + 512 + l16 * 32 + quad * 8);
        for (int n2 = 0; n2 < 12; n2++) {
            bf16x8 bv0 = *(const bf16x8*)(Vs + (n2 * 16 + l16) * 32 + quad * 8);
            bf16x8 bv1 = *(const bf16x8*)(Vs + 6144 + (n2 * 16 + l16) * 32 + quad * 8);
            o[n2] = __builtin_amdgcn_mfma_f32_16x16x32_bf16(ap0, bv0, o[n2], 0, 0, 0);
            o[n2] = __builtin_amdgcn_mfma_f32_16x16x32_bf16(ap1, bv1, o[n2], 0, 0, 0);
        }
        __syncthreads();
    }

    int b = bh >> 4, h = bh & 15;
    for (int n2 = 0; n2 < 12; n2++)
        for (int r = 0; r < 4; r++) {
            float val = o[n2][r] / l_i[r];
            int l = qt * 64 + wave * 16 + quad * 4 + r;
            ao[(((size_t)(b * L_ + l)) * H_ + h) * DQ_ + n2 * 16 + l16] = f2bf(val);
        }
}

extern "C" void kernel_launch(void* const* d_in, const int* in_sizes, int n_in,
                              void* d_out, int out_size, void* d_ws, size_t ws_size,
                              hipStream_t stream) {
    const float* x    = (const float*)d_in[0];
    const float* cosT = (const float*)d_in[1];
    const float* sinT = (const float*)d_in[2];
    const float* wq   = (const float*)d_in[3];
    const float* wkv  = (const float*)d_in[4];
    const float* wup  = (const float*)d_in[5];
    const float* wout = (const float*)d_in[6];
    float* out = (float*)d_out;
    char* ws = (char*)d_ws;

    size_t off = 0;
    auto alloc = [&](size_t b) { size_t r = off; off += (b + 255) & ~(size_t)255; return r; };
    u16* xb     = (u16*)(ws + alloc((size_t)M_ * E_ * 2));
    u16* wqT    = (u16*)(ws + alloc((size_t)NQ_ * E_ * 2));
    u16* wkvT   = (u16*)(ws + alloc((size_t)NKVP_ * E_ * 2));
    u16* wupT   = (u16*)(ws + alloc((size_t)NUP_ * RK_ * 2));
    u16* woutT  = (u16*)(ws + alloc((size_t)E_ * NQ_ * 2));
    u16* qb     = (u16*)(ws + alloc((size_t)M_ * DQ_ * H_ * 2 / 1 * 1));   // (B*H,L,192)
    u16* kb     = (u16*)(ws + alloc((size_t)B_ * H_ * L_ * DQ_ * 2));
    u16* vtb    = (u16*)(ws + alloc((size_t)B_ * H_ * DQ_ * L_ * 2));
    u16* ao     = (u16*)(ws + alloc((size_t)M_ * NQ_ * 2));
    u16* ckv    = (u16*)(ws + alloc((size_t)M_ * RK_ * 2));
    u16* kropeb = (u16*)(ws + alloc((size_t)M_ * RD_ * 2));
    char* scratch = ws + alloc((size_t)M_ * NUP_ * 4);   // 84 MB union region
    float* q_all  = (float*)(scratch);                    // M x 3072 fp32 (50.3MB)
    float* kv_lat = (float*)(scratch + (size_t)M_ * NQ_ * 4); // M x 640 fp32 (10.5MB)
    float* up     = (float*)(scratch);                    // M x 5120 fp32 (aliases both)

    dim3 tb(32, 8);
    int n4 = M_ * E_ / 4;
    convert_bf16<<<(n4 + 255) / 256, 256, 0, stream>>>(x, xb, n4);
    transpose_w<<<dim3(NQ_ / 32, E_ / 32), tb, 0, stream>>>(wq, wqT, E_, NQ_, NQ_);
    transpose_w<<<dim3(NKVP_ / 32, E_ / 32), tb, 0, stream>>>(wkv, wkvT, E_, NKV_, NKVP_);
    transpose_w<<<dim3(NUP_ / 32, RK_ / 32), tb, 0, stream>>>(wup, wupT, RK_, NUP_, NUP_);
    transpose_w<<<dim3(E_ / 32, NQ_ / 32), tb, 0, stream>>>(wout, woutT, NQ_, E_, E_);

    gemm_bt<<<dim3(NQ_ / 128, M_ / 128), 256, 0, stream>>>(xb, wqT, q_all, M_, NQ_, E_);
    gemm_bt<<<dim3(NKVP_ / 128, M_ / 128), 256, 0, stream>>>(xb, wkvT, kv_lat, M_, NKVP_, E_);

    int nq = M_ * H_ * 96;
    build_q<<<(nq + 255) / 256, 256, 0, stream>>>(q_all, cosT, sinT, qb);
    int nc = M_ * 288;
    build_ckv<<<(nc + 255) / 256, 256, 0, stream>>>(kv_lat, cosT, sinT, ckv, kropeb);

    gemm_bt<<<dim3(NUP_ / 128, M_ / 128), 256, 0, stream>>>(ckv, wupT, up, M_, NUP_, RK_);
    build_kvt<<<B_ * H_ * 32, 256, 0, stream>>>(up, kropeb, kb, vtb);

    attn<<<dim3(L_ / 64, B_ * H_), 256, 0, stream>>>(qb, kb, vtb, ao);

    gemm_bt<<<dim3(E_ / 128, M_ / 128), 256, 0, stream>>>(ao, woutT, out, M_, E_, NQ_);
}

// Round 2
// 695.651 us; speedup vs baseline: 1.0229x; 1.0229x over previous
//
#include <hip/hip_runtime.h>
#include <stdint.h>

#define H_ 16
#define DH_ 128
#define RK_ 512
#define RD_ 64
#define B_ 2
#define L_ 2048
#define E_ 2048
#define DQ_ 192            // DH+RD
#define NQ_ (H_*DQ_)       // 3072
#define NKV_ 576
#define NKVP_ 640
#define NUP_ (H_*(2*DH_+RD_)) // 5120
#define M_ (B_*L_)         // 4096

typedef unsigned short u16;
typedef __bf16 bf16x8 __attribute__((ext_vector_type(8)));
typedef float floatx4 __attribute__((ext_vector_type(4)));

__device__ __forceinline__ u16 f2bf(float f) {
    union { float f; uint32_t u; } v; v.f = f;
    uint32_t u = v.u;
    u = (u + 0x7fffu + ((u >> 16) & 1u)) >> 16;
    return (u16)u;
}

__device__ __forceinline__ void gld_lds16(const void* g, void* l) {
    __builtin_amdgcn_global_load_lds((__attribute__((address_space(1))) void*)(g),
                                     (__attribute__((address_space(3))) void*)(l),
                                     16, 0, 0);
}

// ---------------- fp32 -> bf16 elementwise (x) ----------------
__global__ void convert_bf16(const float* __restrict__ in, u16* __restrict__ out, int n4) {
    int i = blockIdx.x * blockDim.x + threadIdx.x;
    if (i >= n4) return;
    float4 v = ((const float4*)in)[i];
    uint2 o;
    o.x = (uint32_t)f2bf(v.x) | ((uint32_t)f2bf(v.y) << 16);
    o.y = (uint32_t)f2bf(v.z) | ((uint32_t)f2bf(v.w) << 16);
    ((uint2*)out)[i] = o;
}

// ---------------- W (KxN fp32) -> Wt (Npad x K bf16), zero pad ----------------
__global__ void transpose_w(const float* __restrict__ W, u16* __restrict__ Wt,
                            int K, int N, int Npad) {
    __shared__ float tile[32][33];
    int n0 = blockIdx.x * 32, k0 = blockIdx.y * 32;
    int tx = threadIdx.x, ty = threadIdx.y; // 32 x 8
    for (int i = 0; i < 4; i++) {
        int k = k0 + ty + i * 8, n = n0 + tx;
        tile[ty + i * 8][tx] = (n < N) ? W[(size_t)k * N + n] : 0.f;
    }
    __syncthreads();
    for (int i = 0; i < 4; i++) {
        int n = n0 + ty + i * 8, k = k0 + tx;
        Wt[(size_t)n * K + k] = f2bf(tile[tx][ty + i * 8]);
    }
}

// ---------------- GEMM: C(MxN fp32) = A(MxK bf16) * Bt(NxK bf16)^T ----------------
__global__ __launch_bounds__(256) void gemm_bt(const u16* __restrict__ A,
                                               const u16* __restrict__ Bt,
                                               float* __restrict__ C,
                                               int M, int N, int K) {
    __shared__ __align__(16) u16 As[128 * 32];
    __shared__ __align__(16) u16 Bs[128 * 32];
    const int tid = threadIdx.x;
    const int wave = tid >> 6, lane = tid & 63;
    const int quad = lane >> 4, l16 = lane & 15;
    const int m0 = blockIdx.y * 128, n0 = blockIdx.x * 128;
    const int wm = (wave >> 1) * 64, wn = (wave & 1) * 64;

    floatx4 zero4 = {0.f, 0.f, 0.f, 0.f};
    floatx4 acc[4][4];
    for (int i = 0; i < 4; i++) for (int j = 0; j < 4; j++) acc[i][j] = zero4;

    const u16* Ab = A + (size_t)m0 * K;
    const u16* Bb = Bt + (size_t)n0 * K;

    for (int k0 = 0; k0 < K; k0 += 32) {
        for (int it = 0; it < 2; ++it) {
            int c = it * 256 + tid;
            int row = c >> 2, cr = c & 3;
            gld_lds16(Ab + (size_t)row * K + k0 + cr * 8, As + c * 8);
            gld_lds16(Bb + (size_t)row * K + k0 + cr * 8, Bs + c * 8);
        }
        __syncthreads();
        bf16x8 af[4], bfr[4];
        for (int i = 0; i < 4; i++) af[i]  = *(const bf16x8*)(As + (wm + i * 16 + l16) * 32 + quad * 8);
        for (int j = 0; j < 4; j++) bfr[j] = *(const bf16x8*)(Bs + (wn + j * 16 + l16) * 32 + quad * 8);
        for (int i = 0; i < 4; i++)
            for (int j = 0; j < 4; j++)
                acc[i][j] = __builtin_amdgcn_mfma_f32_16x16x32_bf16(af[i], bfr[j], acc[i][j], 0, 0, 0);
        __syncthreads();
    }
    for (int i = 0; i < 4; i++)
        for (int j = 0; j < 4; j++) {
            int mrow = m0 + wm + i * 16 + quad * 4;
            int ncol = n0 + wn + j * 16 + l16;
            float* Cp = C + (size_t)mrow * N + ncol;
            for (int r = 0; r < 4; r++) Cp[(size_t)r * N] = acc[i][j][r];
        }
}

// ---------------- build q: rope + scale*log2e + layout (B,H,L,192) bf16 ----------------
__global__ void build_q(const float* __restrict__ q_all, const float* __restrict__ cosT,
                        const float* __restrict__ sinT, u16* __restrict__ qb) {
    const float QS = 0.07216878364870323f * 1.4426950408889634f; // 1/sqrt(192) * log2(e)
    int idx = blockIdx.x * blockDim.x + threadIdx.x;
    if (idx >= M_ * H_ * 96) return;
    int p = idx % 96; int t = idx / 96; int h = t % H_; int row = t / H_;
    int l = row & (L_ - 1); int b = row >> 11;
    const float* src = q_all + (size_t)row * NQ_ + h * DQ_;
    u16* dst = qb + ((size_t)(b * H_ + h) * L_ + l) * DQ_;
    int d = 2 * p;
    float x1 = src[d], x2 = src[d + 1];
    if (d < DH_) { dst[d] = f2bf(x1 * QS); dst[d + 1] = f2bf(x2 * QS); }
    else {
        int i = (d - DH_) >> 1;
        float c = cosT[(size_t)l * 32 + i], s = sinT[(size_t)l * 32 + i];
        dst[d]     = f2bf((x1 * c - x2 * s) * QS);
        dst[d + 1] = f2bf((x1 * s + x2 * c) * QS);
    }
}

// ---------------- build c_kv (bf16) + roped k_rope (bf16) ----------------
__global__ void build_ckv(const float* __restrict__ kv, const float* __restrict__ cosT,
                          const float* __restrict__ sinT, u16* __restrict__ ckv,
                          u16* __restrict__ kropeb) {
    int idx = blockIdx.x * blockDim.x + threadIdx.x;
    if (idx >= M_ * 288) return;
    int j = idx % 288; int row = idx / 288;
    int l = row & (L_ - 1);
    const float* src = kv + (size_t)row * NKVP_;
    if (j < 256) {
        ckv[(size_t)row * RK_ + 2 * j]     = f2bf(src[2 * j]);
        ckv[(size_t)row * RK_ + 2 * j + 1] = f2bf(src[2 * j + 1]);
    } else {
        int i = j - 256;
        float x1 = src[RK_ + 2 * i], x2 = src[RK_ + 2 * i + 1];
        float c = cosT[(size_t)l * 32 + i], s = sinT[(size_t)l * 32 + i];
        kropeb[(size_t)row * RD_ + 2 * i]     = f2bf(x1 * c - x2 * s);
        kropeb[(size_t)row * RD_ + 2 * i + 1] = f2bf(x1 * s + x2 * c);
    }
}

// ---------------- build k (B,H,L,192) + vT (B,H,192,L perm) bf16 ----------------
// vtb stores s-index permuted within each 32-group: k = ((s>>2)&3)*8 + ((s>>4)&1)*4 + (s&3)
// so that MFMA B-frag element j at lane quad (k=quad*8+j) matches S^T C-layout rows.
__global__ __launch_bounds__(256) void build_kvt(const float* __restrict__ up,
        const u16* __restrict__ kropeb, u16* __restrict__ kb, u16* __restrict__ vtb) {
    __shared__ float vt[64][193];
    int blk = blockIdx.x;          // (b*H+h)*32 + lt
    int lt = blk & 31; int bh = blk >> 5; int h = bh % H_; int b = bh / H_;
    int tid = threadIdx.x;
    int l0 = lt * 64;
    for (int it = 0; it < 48; ++it) {
        int idx = it * 256 + tid;  // 64*192
        int lr = idx / 192, d = idx % 192;
        size_t row = (size_t)b * L_ + l0 + lr;
        float vv = (d < DH_) ? up[row * NUP_ + h * 320 + DH_ + d]
                             : up[row * NUP_ + h * 320 + 2 * DH_ + (d - DH_)];
        vt[lr][d] = vv;
        u16 kbf = (d < DH_) ? f2bf(up[row * NUP_ + h * 320 + d])
                            : kropeb[row * RD_ + (d - DH_)];
        kb[((size_t)bh * L_ + l0 + lr) * DQ_ + d] = kbf;
    }
    __syncthreads();
    for (int it = 0; it < 48; ++it) {
        int idx = it * 256 + tid;
        int lr = idx & 63, d = idx >> 6;
        int l = l0 + lr;
        int s5 = l & 31;
        int k5 = ((s5 >> 2) & 3) * 8 + ((s5 >> 4) & 1) * 4 + (s5 & 3);
        int lp = (l & ~31) | k5;
        vtb[((size_t)bh * DQ_ + d) * L_ + lp] = f2bf(vt[lr][d]);
    }
}

// ---------------- flash attention, causal, S^T formulation ----------------
// Q-tile 128/block: wave w owns q rows {w*16..} (a=0) and {64+w*16..} (a=1).
// Per lane: l16 = q row, softmax state scalar. P feeds PV directly from regs
// via the vtb k-permutation. LDS: K panels [kk6][64][32], V [g2][192][32perm].
__global__ __launch_bounds__(256) void attn(const u16* __restrict__ qb,
        const u16* __restrict__ kb, const u16* __restrict__ vtb, u16* __restrict__ ao) {
    __shared__ __align__(16) u16 Ks[6 * 64 * 32];
    __shared__ __align__(16) u16 Vs[2 * 192 * 32];
    int idx = blockIdx.x;
    int cb = idx & 255, pp = idx >> 8;
    int t = cb & 7, bh = cb >> 3;
    int qt = pp ? t : 15 - t;           // pair (15-t, t) on same CU: constant work
    int tid = threadIdx.x, wave = tid >> 6, lane = tid & 63;
    int quad = lane >> 4, l16 = lane & 15;

    bf16x8 aq[2][6];
    const u16* qbase = qb + ((size_t)bh * L_ + qt * 128 + wave * 16 + l16) * DQ_;
    for (int a = 0; a < 2; a++)
        for (int kk = 0; kk < 6; kk++)
            aq[a][kk] = *(const bf16x8*)(qbase + a * 64 * DQ_ + kk * 32 + quad * 8);

    floatx4 zero4 = {0.f, 0.f, 0.f, 0.f};
    floatx4 o[2][12];
    for (int a = 0; a < 2; a++) for (int i = 0; i < 12; i++) o[a][i] = zero4;
    float m_i[2] = {-INFINITY, -INFINITY};
    float l_i[2] = {0.f, 0.f};

    const u16* kbase0 = kb + (size_t)bh * L_ * DQ_;
    const u16* vbase0 = vtb + (size_t)bh * (size_t)DQ_ * L_;
    const int stend = 2 * qt + 1;

    for (int st = 0; st <= stend; ++st) {
        const u16* kg = kbase0 + (size_t)st * 64 * DQ_;
        for (int it = 0; it < 6; ++it) {
            int c = it * 256 + tid;
            int s = tid >> 2, q4 = tid & 3;
            gld_lds16(kg + (size_t)s * DQ_ + it * 32 + q4 * 8, Ks + c * 8);
        }
        const u16* vg = vbase0 + st * 64;
        for (int it = 0; it < 6; ++it) {
            int c = it * 256 + tid;
            int g = (c >= 768) ? 1 : 0;
            int cc = c - g * 768;
            int d = cc >> 2, q4 = cc & 3;
            gld_lds16(vg + (size_t)d * L_ + g * 32 + q4 * 8, Vs + c * 8);
        }
        __syncthreads();

        bf16x8 pf[2][2];
        bool a0_live = (st <= 2 * qt);
        for (int a = 0; a < 2; a++) {
            int mode;  // 0=full, 1=diag, 2=skip
            if (a == 0) mode = (st < 2 * qt) ? 0 : ((st == 2 * qt) ? 1 : 2);
            else        mode = (st < stend) ? 0 : 1;
            if (mode == 2) continue;

            float pv[4][4];
            int smax = (mode == 1) ? wave : 3;
            if (mode == 1)
                for (int i = 0; i < 4; i++) for (int r = 0; r < 4; r++) pv[i][r] = 0.f;
            float mx = -INFINITY;
            for (int stile = 0; stile <= smax; ++stile) {
                floatx4 sacc = zero4;
                for (int kk = 0; kk < 6; kk++) {
                    bf16x8 kf = *(const bf16x8*)(Ks + kk * 2048 + (stile * 16 + l16) * 32 + quad * 8);
                    sacc = __builtin_amdgcn_mfma_f32_16x16x32_bf16(kf, aq[a][kk], sacc, 0, 0, 0);
                }
                if (mode == 1 && stile == smax) {
                    for (int r = 0; r < 4; r++) {
                        float v = (quad * 4 + r > l16) ? -1e30f : sacc[r];
                        pv[stile][r] = v;
                        mx = fmaxf(mx, v);
                    }
                } else {
                    for (int r = 0; r < 4; r++) {
                        pv[stile][r] = sacc[r];
                        mx = fmaxf(mx, sacc[r]);
                    }
                }
            }
            mx = fmaxf(mx, __shfl_xor(mx, 16));
            mx = fmaxf(mx, __shfl_xor(mx, 32));
            float mn = fmaxf(m_i[a], mx);
            float alpha = exp2f(m_i[a] - mn);
            m_i[a] = mn;
            float rs = 0.f;
            for (int stile = 0; stile <= smax; ++stile)
                for (int r = 0; r < 4; r++) {
                    float e = exp2f(pv[stile][r] - mn);
                    pv[stile][r] = e;
                    rs += e;
                }
            rs += __shfl_xor(rs, 16);
            rs += __shfl_xor(rs, 32);
            l_i[a] = l_i[a] * alpha + rs;
            if (__any(alpha != 1.0f))
                for (int i = 0; i < 12; i++) o[a][i] *= alpha;
            for (int g = 0; g < 2; g++) {
                union { bf16x8 v; u16 s[8]; } u;
                for (int r = 0; r < 4; r++) {
                    u.s[r]     = f2bf(pv[g * 2][r]);
                    u.s[4 + r] = f2bf(pv[g * 2 + 1][r]);
                }
                pf[a][g] = u.v;
            }
        }

        for (int g = 0; g < 2; g++)
            for (int dtile = 0; dtile < 12; dtile++) {
                bf16x8 vf = *(const bf16x8*)(Vs + g * 6144 + (dtile * 16 + l16) * 32 + quad * 8);
                if (a0_live)
                    o[0][dtile] = __builtin_amdgcn_mfma_f32_16x16x32_bf16(vf, pf[0][g], o[0][dtile], 0, 0, 0);
                o[1][dtile] = __builtin_amdgcn_mfma_f32_16x16x32_bf16(vf, pf[1][g], o[1][dtile], 0, 0, 0);
            }
        __syncthreads();
    }

    int b = bh >> 4, h = bh & 15;
    for (int a = 0; a < 2; a++) {
        float inv = 1.0f / l_i[a];
        int l = qt * 128 + a * 64 + wave * 16 + l16;
        u16* dst = ao + (((size_t)(b * L_ + l)) * H_ + h) * DQ_;
        for (int dtile = 0; dtile < 12; dtile++) {
            ushort4 pk;
            pk.x = f2bf(o[a][dtile][0] * inv);
            pk.y = f2bf(o[a][dtile][1] * inv);
            pk.z = f2bf(o[a][dtile][2] * inv);
            pk.w = f2bf(o[a][dtile][3] * inv);
            *(ushort4*)(dst + dtile * 16 + quad * 4) = pk;
        }
    }
}

extern "C" void kernel_launch(void* const* d_in, const int* in_sizes, int n_in,
                              void* d_out, int out_size, void* d_ws, size_t ws_size,
                              hipStream_t stream) {
    const float* x    = (const float*)d_in[0];
    const float* cosT = (const float*)d_in[1];
    const float* sinT = (const float*)d_in[2];
    const float* wq   = (const float*)d_in[3];
    const float* wkv  = (const float*)d_in[4];
    const float* wup  = (const float*)d_in[5];
    const float* wout = (const float*)d_in[6];
    float* out = (float*)d_out;
    char* ws = (char*)d_ws;

    size_t off = 0;
    auto alloc = [&](size_t b) { size_t r = off; off += (b + 255) & ~(size_t)255; return r; };
    u16* xb     = (u16*)(ws + alloc((size_t)M_ * E_ * 2));
    u16* wqT    = (u16*)(ws + alloc((size_t)NQ_ * E_ * 2));
    u16* wkvT   = (u16*)(ws + alloc((size_t)NKVP_ * E_ * 2));
    u16* wupT   = (u16*)(ws + alloc((size_t)NUP_ * RK_ * 2));
    u16* woutT  = (u16*)(ws + alloc((size_t)E_ * NQ_ * 2));
    u16* qb     = (u16*)(ws + alloc((size_t)B_ * H_ * L_ * DQ_ * 2));
    u16* kb     = (u16*)(ws + alloc((size_t)B_ * H_ * L_ * DQ_ * 2));
    u16* vtb    = (u16*)(ws + alloc((size_t)B_ * H_ * DQ_ * L_ * 2));
    u16* ao     = (u16*)(ws + alloc((size_t)M_ * NQ_ * 2));
    u16* ckv    = (u16*)(ws + alloc((size_t)M_ * RK_ * 2));
    u16* kropeb = (u16*)(ws + alloc((size_t)M_ * RD_ * 2));
    char* scratch = ws + alloc((size_t)M_ * NUP_ * 4);
    float* q_all  = (float*)(scratch);                        // M x 3072 fp32
    float* kv_lat = (float*)(scratch + (size_t)M_ * NQ_ * 4); // M x 640 fp32
    float* up     = (float*)(scratch);                        // M x 5120 fp32 (aliases)

    dim3 tb(32, 8);
    int n4 = M_ * E_ / 4;
    convert_bf16<<<(n4 + 255) / 256, 256, 0, stream>>>(x, xb, n4);
    transpose_w<<<dim3(NQ_ / 32, E_ / 32), tb, 0, stream>>>(wq, wqT, E_, NQ_, NQ_);
    transpose_w<<<dim3(NKVP_ / 32, E_ / 32), tb, 0, stream>>>(wkv, wkvT, E_, NKV_, NKVP_);
    transpose_w<<<dim3(NUP_ / 32, RK_ / 32), tb, 0, stream>>>(wup, wupT, RK_, NUP_, NUP_);
    transpose_w<<<dim3(E_ / 32, NQ_ / 32), tb, 0, stream>>>(wout, woutT, NQ_, E_, E_);

    gemm_bt<<<dim3(NQ_ / 128, M_ / 128), 256, 0, stream>>>(xb, wqT, q_all, M_, NQ_, E_);
    gemm_bt<<<dim3(NKVP_ / 128, M_ / 128), 256, 0, stream>>>(xb, wkvT, kv_lat, M_, NKVP_, E_);

    int nq = M_ * H_ * 96;
    build_q<<<(nq + 255) / 256, 256, 0, stream>>>(q_all, cosT, sinT, qb);
    int nc = M_ * 288;
    build_ckv<<<(nc + 255) / 256, 256, 0, stream>>>(kv_lat, cosT, sinT, ckv, kropeb);

    gemm_bt<<<dim3(NUP_ / 128, M_ / 128), 256, 0, stream>>>(ckv, wupT, up, M_, NUP_, RK_);
    build_kvt<<<B_ * H_ * 32, 256, 0, stream>>>(up, kropeb, kb, vtb);

    attn<<<512, 256, 0, stream>>>(qb, kb, vtb, ao);

    gemm_bt<<<dim3(E_ / 128, M_ / 128), 256, 0, stream>>>(ao, woutT, out, M_, E_, NQ_);
}

// Round 3
// 690.769 us; speedup vs baseline: 1.0301x; 1.0071x over previous
//
#include <hip/hip_runtime.h>
#include <stdint.h>

#define H_ 16
#define DH_ 128
#define RK_ 512
#define RD_ 64
#define B_ 2
#define L_ 2048
#define E_ 2048
#define DQ_ 192            // DH+RD
#define NQ_ (H_*DQ_)       // 3072
#define NKV_ 576
#define NKVP_ 640
#define NUP_ (H_*(2*DH_+RD_)) // 5120
#define M_ (B_*L_)         // 4096

typedef unsigned short u16;
typedef __bf16 bf16x8 __attribute__((ext_vector_type(8)));
typedef float floatx4 __attribute__((ext_vector_type(4)));

__device__ __forceinline__ u16 f2bf(float f) {
    union { float f; uint32_t u; } v; v.f = f;
    uint32_t u = v.u;
    u = (u + 0x7fffu + ((u >> 16) & 1u)) >> 16;
    return (u16)u;
}
__device__ __forceinline__ float bf2f(u16 b) {
    union { uint32_t u; float f; } v; v.u = ((uint32_t)b) << 16; return v.f;
}

__device__ __forceinline__ void gld_lds16(const void* g, void* l) {
    __builtin_amdgcn_global_load_lds((__attribute__((address_space(1))) void*)(g),
                                     (__attribute__((address_space(3))) void*)(l),
                                     16, 0, 0);
}

// ---------------- fp32 -> bf16 elementwise (x) ----------------
__global__ void convert_bf16(const float* __restrict__ in, u16* __restrict__ out, int n4) {
    int i = blockIdx.x * blockDim.x + threadIdx.x;
    if (i >= n4) return;
    float4 v = ((const float4*)in)[i];
    uint2 o;
    o.x = (uint32_t)f2bf(v.x) | ((uint32_t)f2bf(v.y) << 16);
    o.y = (uint32_t)f2bf(v.z) | ((uint32_t)f2bf(v.w) << 16);
    ((uint2*)out)[i] = o;
}

// ---------------- W (KxN fp32) -> Wt (Npad x K bf16), zero pad ----------------
__global__ void transpose_w(const float* __restrict__ W, u16* __restrict__ Wt,
                            int K, int N, int Npad) {
    __shared__ float tile[32][33];
    int n0 = blockIdx.x * 32, k0 = blockIdx.y * 32;
    int tx = threadIdx.x, ty = threadIdx.y; // 32 x 8
    for (int i = 0; i < 4; i++) {
        int k = k0 + ty + i * 8, n = n0 + tx;
        tile[ty + i * 8][tx] = (n < N) ? W[(size_t)k * N + n] : 0.f;
    }
    __syncthreads();
    for (int i = 0; i < 4; i++) {
        int n = n0 + ty + i * 8, k = k0 + tx;
        Wt[(size_t)n * K + k] = f2bf(tile[tx][ty + i * 8]);
    }
}

// ---------------- GEMM: C(MxN fp32) = A(MxK bf16) * Bt(NxK bf16)^T ----------------
__global__ __launch_bounds__(256) void gemm_bt(const u16* __restrict__ A,
                                               const u16* __restrict__ Bt,
                                               float* __restrict__ C,
                                               int M, int N, int K) {
    __shared__ __align__(16) u16 As[128 * 32];
    __shared__ __align__(16) u16 Bs[128 * 32];
    const int tid = threadIdx.x;
    const int wave = tid >> 6, lane = tid & 63;
    const int quad = lane >> 4, l16 = lane & 15;
    const int m0 = blockIdx.y * 128, n0 = blockIdx.x * 128;
    const int wm = (wave >> 1) * 64, wn = (wave & 1) * 64;

    floatx4 zero4 = {0.f, 0.f, 0.f, 0.f};
    floatx4 acc[4][4];
    for (int i = 0; i < 4; i++) for (int j = 0; j < 4; j++) acc[i][j] = zero4;

    const u16* Ab = A + (size_t)m0 * K;
    const u16* Bb = Bt + (size_t)n0 * K;

    for (int k0 = 0; k0 < K; k0 += 32) {
        for (int it = 0; it < 2; ++it) {
            int c = it * 256 + tid;
            int row = c >> 2, cr = c & 3;
            gld_lds16(Ab + (size_t)row * K + k0 + cr * 8, As + c * 8);
            gld_lds16(Bb + (size_t)row * K + k0 + cr * 8, Bs + c * 8);
        }
        __syncthreads();
        bf16x8 af[4], bfr[4];
        for (int i = 0; i < 4; i++) af[i]  = *(const bf16x8*)(As + (wm + i * 16 + l16) * 32 + quad * 8);
        for (int j = 0; j < 4; j++) bfr[j] = *(const bf16x8*)(Bs + (wn + j * 16 + l16) * 32 + quad * 8);
        for (int i = 0; i < 4; i++)
            for (int j = 0; j < 4; j++)
                acc[i][j] = __builtin_amdgcn_mfma_f32_16x16x32_bf16(af[i], bfr[j], acc[i][j], 0, 0, 0);
        __syncthreads();
    }
    for (int i = 0; i < 4; i++)
        for (int j = 0; j < 4; j++) {
            int mrow = m0 + wm + i * 16 + quad * 4;
            int ncol = n0 + wn + j * 16 + l16;
            float* Cp = C + (size_t)mrow * N + ncol;
            for (int r = 0; r < 4; r++) Cp[(size_t)r * N] = acc[i][j][r];
        }
}

// ---------------- build q: rope + scale*log2e + layout (B,H,L,192) bf16 ----------------
__global__ void build_q(const float* __restrict__ q_all, const float* __restrict__ cosT,
                        const float* __restrict__ sinT, u16* __restrict__ qb) {
    const float QS = 0.07216878364870323f * 1.4426950408889634f; // 1/sqrt(192) * log2(e)
    int idx = blockIdx.x * blockDim.x + threadIdx.x;
    if (idx >= M_ * H_ * 96) return;
    int p = idx % 96; int t = idx / 96; int h = t % H_; int row = t / H_;
    int l = row & (L_ - 1); int b = row >> 11;
    const float* src = q_all + (size_t)row * NQ_ + h * DQ_;
    u16* dst = qb + ((size_t)(b * H_ + h) * L_ + l) * DQ_;
    int d = 2 * p;
    float x1 = src[d], x2 = src[d + 1];
    if (d < DH_) { dst[d] = f2bf(x1 * QS); dst[d + 1] = f2bf(x2 * QS); }
    else {
        int i = (d - DH_) >> 1;
        float c = cosT[(size_t)l * 32 + i], s = sinT[(size_t)l * 32 + i];
        dst[d]     = f2bf((x1 * c - x2 * s) * QS);
        dst[d + 1] = f2bf((x1 * s + x2 * c) * QS);
    }
}

// ---------------- build c_kv (bf16) + roped k_rope (bf16) ----------------
__global__ void build_ckv(const float* __restrict__ kv, const float* __restrict__ cosT,
                          const float* __restrict__ sinT, u16* __restrict__ ckv,
                          u16* __restrict__ kropeb) {
    int idx = blockIdx.x * blockDim.x + threadIdx.x;
    if (idx >= M_ * 288) return;
    int j = idx % 288; int row = idx / 288;
    int l = row & (L_ - 1);
    const float* src = kv + (size_t)row * NKVP_;
    if (j < 256) {
        ckv[(size_t)row * RK_ + 2 * j]     = f2bf(src[2 * j]);
        ckv[(size_t)row * RK_ + 2 * j + 1] = f2bf(src[2 * j + 1]);
    } else {
        int i = j - 256;
        float x1 = src[RK_ + 2 * i], x2 = src[RK_ + 2 * i + 1];
        float c = cosT[(size_t)l * 32 + i], s = sinT[(size_t)l * 32 + i];
        kropeb[(size_t)row * RD_ + 2 * i]     = f2bf(x1 * c - x2 * s);
        kropeb[(size_t)row * RD_ + 2 * i + 1] = f2bf(x1 * s + x2 * c);
    }
}

// ---------------- build k (B,H,L,192) + vT (B,H,192,L perm) bf16 ----------------
__global__ __launch_bounds__(256) void build_kvt(const float* __restrict__ up,
        const u16* __restrict__ kropeb, u16* __restrict__ kb, u16* __restrict__ vtb) {
    __shared__ float vt[64][193];
    int blk = blockIdx.x;          // (b*H+h)*32 + lt
    int lt = blk & 31; int bh = blk >> 5; int h = bh % H_; int b = bh / H_;
    int tid = threadIdx.x;
    int l0 = lt * 64;
    for (int it = 0; it < 48; ++it) {
        int idx = it * 256 + tid;  // 64*192
        int lr = idx / 192, d = idx % 192;
        size_t row = (size_t)b * L_ + l0 + lr;
        float vv = (d < DH_) ? up[row * NUP_ + h * 320 + DH_ + d]
                             : up[row * NUP_ + h * 320 + 2 * DH_ + (d - DH_)];
        vt[lr][d] = vv;
        u16 kbf = (d < DH_) ? f2bf(up[row * NUP_ + h * 320 + d])
                            : kropeb[row * RD_ + (d - DH_)];
        kb[((size_t)bh * L_ + l0 + lr) * DQ_ + d] = kbf;
    }
    __syncthreads();
    for (int it = 0; it < 48; ++it) {
        int idx = it * 256 + tid;
        int lr = idx & 63, d = idx >> 6;
        int l = l0 + lr;
        int s5 = l & 31;
        int k5 = ((s5 >> 2) & 3) * 8 + ((s5 >> 4) & 1) * 4 + (s5 & 3);
        int lp = (l & ~31) | k5;
        vtb[((size_t)bh * DQ_ + d) * L_ + lp] = f2bf(vt[lr][d]);
    }
}

// ---------------- flash attention, causal, S^T, split-s halves ----------------
// 512 blocks, each EXACTLY 17 st-iters: block(bh,t,j) runs half-j of tile 15-t
// then half-j of tile t. Partials (o bf16 unnormalized, m/l f32) to ws; merged
// by attn_merge. 8 waves/CU resident for the whole kernel.
__global__ __launch_bounds__(256) void attn(const u16* __restrict__ qb,
        const u16* __restrict__ kb, const u16* __restrict__ vtb,
        u16* __restrict__ po0, u16* __restrict__ po1,
        float* __restrict__ pm0, float* __restrict__ pl0,
        float* __restrict__ pm1, float* __restrict__ pl1) {
    __shared__ __align__(16) u16 Ks[6 * 64 * 32];
    __shared__ __align__(16) u16 Vs[2 * 192 * 32];
    int blk = blockIdx.x;
    int j = blk & 1, t = (blk >> 1) & 7, bh = blk >> 4;
    int tid = threadIdx.x, wave = tid >> 6, lane = tid & 63;
    int quad = lane >> 4, l16 = lane & 15;

    u16* po = j ? po1 : po0;
    float* pm = j ? pm1 : pm0;
    float* pl = j ? pl1 : pl0;

    const u16* kbase0 = kb + (size_t)bh * L_ * DQ_;
    const u16* vbase0 = vtb + (size_t)bh * (size_t)DQ_ * L_;
    floatx4 zero4 = {0.f, 0.f, 0.f, 0.f};

    for (int seg = 0; seg < 2; ++seg) {
        const int qt = seg == 0 ? (15 - t) : t;
        const int st0 = j ? (qt + 1) : 0;
        const int st1 = j ? (2 * qt + 1) : qt;

        bf16x8 aq[2][6];
        const u16* qbase = qb + ((size_t)bh * L_ + qt * 128 + wave * 16 + l16) * DQ_;
        for (int a = 0; a < 2; a++)
            for (int kk = 0; kk < 6; kk++)
                aq[a][kk] = *(const bf16x8*)(qbase + a * 64 * DQ_ + kk * 32 + quad * 8);

        floatx4 o[2][12];
        for (int a = 0; a < 2; a++) for (int i = 0; i < 12; i++) o[a][i] = zero4;
        float m_i[2] = {-INFINITY, -INFINITY};
        float l_i[2] = {0.f, 0.f};

        for (int st = st0; st <= st1; ++st) {
            const u16* kg = kbase0 + (size_t)st * 64 * DQ_;
            for (int it = 0; it < 6; ++it) {
                int c = it * 256 + tid;
                int s = tid >> 2, q4 = tid & 3;
                gld_lds16(kg + (size_t)s * DQ_ + it * 32 + q4 * 8, Ks + c * 8);
            }
            const u16* vg = vbase0 + st * 64;
            for (int it = 0; it < 6; ++it) {
                int c = it * 256 + tid;
                int g = (c >= 768) ? 1 : 0;
                int cc = c - g * 768;
                int d = cc >> 2, q4 = cc & 3;
                gld_lds16(vg + (size_t)d * L_ + g * 32 + q4 * 8, Vs + c * 8);
            }
            __syncthreads();

            float pv[2][4][4];
            bf16x8 pf[2][2];
            bool a0_live = (st <= 2 * qt);

            if (st < 2 * qt) {
                // fused full path: read each K-frag once, feed both Q row-sets
                float mx0 = -INFINITY, mx1 = -INFINITY;
                for (int stile = 0; stile < 4; ++stile) {
                    floatx4 s0 = zero4, s1 = zero4;
                    for (int kk = 0; kk < 6; kk++) {
                        bf16x8 kf = *(const bf16x8*)(Ks + kk * 2048 + (stile * 16 + l16) * 32 + quad * 8);
                        s0 = __builtin_amdgcn_mfma_f32_16x16x32_bf16(kf, aq[0][kk], s0, 0, 0, 0);
                        s1 = __builtin_amdgcn_mfma_f32_16x16x32_bf16(kf, aq[1][kk], s1, 0, 0, 0);
                    }
                    for (int r = 0; r < 4; r++) {
                        pv[0][stile][r] = s0[r]; mx0 = fmaxf(mx0, s0[r]);
                        pv[1][stile][r] = s1[r]; mx1 = fmaxf(mx1, s1[r]);
                    }
                }
                float mxx[2] = {mx0, mx1};
                for (int a = 0; a < 2; a++) {
                    float mx = mxx[a];
                    mx = fmaxf(mx, __shfl_xor(mx, 16));
                    mx = fmaxf(mx, __shfl_xor(mx, 32));
                    float mn = fmaxf(m_i[a], mx);
                    float alpha = exp2f(m_i[a] - mn);
                    m_i[a] = mn;
                    float rs = 0.f;
                    for (int stile = 0; stile < 4; ++stile)
                        for (int r = 0; r < 4; r++) {
                            float e = exp2f(pv[a][stile][r] - mn);
                            pv[a][stile][r] = e;
                            rs += e;
                        }
                    rs += __shfl_xor(rs, 16);
                    rs += __shfl_xor(rs, 32);
                    l_i[a] = l_i[a] * alpha + rs;
                    if (__any(alpha != 1.0f))
                        for (int i = 0; i < 12; i++) o[a][i] *= alpha;
                    for (int g = 0; g < 2; g++) {
                        union { bf16x8 v; u16 s[8]; } u;
                        for (int r = 0; r < 4; r++) {
                            u.s[r]     = f2bf(pv[a][g * 2][r]);
                            u.s[4 + r] = f2bf(pv[a][g * 2 + 1][r]);
                        }
                        pf[a][g] = u.v;
                    }
                }
            } else {
                // tail: diagonal / skip handling per a
                for (int a = 0; a < 2; a++) {
                    int mode;  // 0=full, 1=diag, 2=skip
                    if (a == 0) mode = (st == 2 * qt) ? 1 : 2;
                    else        mode = (st < 2 * qt + 1) ? 0 : 1;
                    if (mode == 2) { continue; }
                    int smax = (mode == 1) ? wave : 3;
                    if (mode == 1)
                        for (int i = 0; i < 4; i++) for (int r = 0; r < 4; r++) pv[a][i][r] = 0.f;
                    float mx = -INFINITY;
                    for (int stile = 0; stile <= smax; ++stile) {
                        floatx4 sacc = zero4;
                        for (int kk = 0; kk < 6; kk++) {
                            bf16x8 kf = *(const bf16x8*)(Ks + kk * 2048 + (stile * 16 + l16) * 32 + quad * 8);
                            sacc = __builtin_amdgcn_mfma_f32_16x16x32_bf16(kf, aq[a][kk], sacc, 0, 0, 0);
                        }
                        if (mode == 1 && stile == smax) {
                            for (int r = 0; r < 4; r++) {
                                float v = (quad * 4 + r > l16) ? -1e30f : sacc[r];
                                pv[a][stile][r] = v;
                                mx = fmaxf(mx, v);
                            }
                        } else {
                            for (int r = 0; r < 4; r++) {
                                pv[a][stile][r] = sacc[r];
                                mx = fmaxf(mx, sacc[r]);
                            }
                        }
                    }
                    mx = fmaxf(mx, __shfl_xor(mx, 16));
                    mx = fmaxf(mx, __shfl_xor(mx, 32));
                    float mn = fmaxf(m_i[a], mx);
                    float alpha = exp2f(m_i[a] - mn);
                    m_i[a] = mn;
                    float rs = 0.f;
                    for (int stile = 0; stile <= smax; ++stile)
                        for (int r = 0; r < 4; r++) {
                            float e = exp2f(pv[a][stile][r] - mn);
                            pv[a][stile][r] = e;
                            rs += e;
                        }
                    rs += __shfl_xor(rs, 16);
                    rs += __shfl_xor(rs, 32);
                    l_i[a] = l_i[a] * alpha + rs;
                    if (__any(alpha != 1.0f))
                        for (int i = 0; i < 12; i++) o[a][i] *= alpha;
                    for (int g = 0; g < 2; g++) {
                        union { bf16x8 v; u16 s[8]; } u;
                        for (int r = 0; r < 4; r++) {
                            u.s[r]     = f2bf(pv[a][g * 2][r]);
                            u.s[4 + r] = f2bf(pv[a][g * 2 + 1][r]);
                        }
                        pf[a][g] = u.v;
                    }
                }
            }

            for (int g = 0; g < 2; g++)
                for (int dtile = 0; dtile < 12; dtile++) {
                    bf16x8 vf = *(const bf16x8*)(Vs + g * 6144 + (dtile * 16 + l16) * 32 + quad * 8);
                    if (a0_live)
                        o[0][dtile] = __builtin_amdgcn_mfma_f32_16x16x32_bf16(vf, pf[0][g], o[0][dtile], 0, 0, 0);
                    o[1][dtile] = __builtin_amdgcn_mfma_f32_16x16x32_bf16(vf, pf[1][g], o[1][dtile], 0, 0, 0);
                }
            __syncthreads();
        }

        // write partials: po[tile][q 128][d 192] bf16, pm/pl[tile][q 128]
        int tile = bh * 16 + qt;
        for (int a = 0; a < 2; a++) {
            int q = a * 64 + wave * 16 + l16;
            u16* dst = po + ((size_t)tile * 128 + q) * 192;
            for (int dtile = 0; dtile < 12; dtile++) {
                ushort4 pk;
                pk.x = f2bf(o[a][dtile][0]);
                pk.y = f2bf(o[a][dtile][1]);
                pk.z = f2bf(o[a][dtile][2]);
                pk.w = f2bf(o[a][dtile][3]);
                *(ushort4*)(dst + dtile * 16 + quad * 4) = pk;
            }
            if (quad == 0) {
                pm[(size_t)tile * 128 + q] = m_i[a];
                pl[(size_t)tile * 128 + q] = l_i[a];
            }
        }
        __syncthreads();
    }
}

// ---------------- merge the two split-s halves -> ao (B,L,H,192) bf16 ----------------
__global__ void attn_merge(const u16* __restrict__ po0, const u16* __restrict__ po1,
                           const float* __restrict__ pm0, const float* __restrict__ pl0,
                           const float* __restrict__ pm1, const float* __restrict__ pl1,
                           u16* __restrict__ ao) {
    int idx = blockIdx.x * blockDim.x + threadIdx.x;   // 512*128*48
    int c = idx % 48; int rest = idx / 48;
    int q = rest & 127; int tile = rest >> 7;
    int bh = tile >> 4, qt = tile & 15;
    size_t mi = (size_t)tile * 128 + q;
    float m0 = pm0[mi], m1 = pm1[mi];
    float l0 = pl0[mi], l1 = pl1[mi];
    float m = fmaxf(m0, m1);
    float a0 = exp2f(m0 - m), a1 = exp2f(m1 - m);
    float inv = 1.0f / (l0 * a0 + l1 * a1);
    float s0 = a0 * inv, s1 = a1 * inv;
    ushort4 u0 = *(const ushort4*)(po0 + mi * 192 + c * 4);
    ushort4 u1 = *(const ushort4*)(po1 + mi * 192 + c * 4);
    int b = bh >> 4, h = bh & 15;
    int l = qt * 128 + q;
    u16* dst = ao + (((size_t)(b * L_ + l)) * H_ + h) * DQ_ + c * 4;
    ushort4 pk;
    pk.x = f2bf(bf2f(u0.x) * s0 + bf2f(u1.x) * s1);
    pk.y = f2bf(bf2f(u0.y) * s0 + bf2f(u1.y) * s1);
    pk.z = f2bf(bf2f(u0.z) * s0 + bf2f(u1.z) * s1);
    pk.w = f2bf(bf2f(u0.w) * s0 + bf2f(u1.w) * s1);
    *(ushort4*)dst = pk;
}

extern "C" void kernel_launch(void* const* d_in, const int* in_sizes, int n_in,
                              void* d_out, int out_size, void* d_ws, size_t ws_size,
                              hipStream_t stream) {
    const float* x    = (const float*)d_in[0];
    const float* cosT = (const float*)d_in[1];
    const float* sinT = (const float*)d_in[2];
    const float* wq   = (const float*)d_in[3];
    const float* wkv  = (const float*)d_in[4];
    const float* wup  = (const float*)d_in[5];
    const float* wout = (const float*)d_in[6];
    float* out = (float*)d_out;
    char* ws = (char*)d_ws;

    size_t off = 0;
    auto alloc = [&](size_t b) { size_t r = off; off += (b + 255) & ~(size_t)255; return r; };
    u16* xb     = (u16*)(ws + alloc((size_t)M_ * E_ * 2));
    u16* wqT    = (u16*)(ws + alloc((size_t)NQ_ * E_ * 2));
    u16* wkvT   = (u16*)(ws + alloc((size_t)NKVP_ * E_ * 2));
    u16* wupT   = (u16*)(ws + alloc((size_t)NUP_ * RK_ * 2));
    u16* woutT  = (u16*)(ws + alloc((size_t)E_ * NQ_ * 2));
    u16* qb     = (u16*)(ws + alloc((size_t)B_ * H_ * L_ * DQ_ * 2));
    u16* kb     = (u16*)(ws + alloc((size_t)B_ * H_ * L_ * DQ_ * 2));
    u16* vtb    = (u16*)(ws + alloc((size_t)B_ * H_ * DQ_ * L_ * 2));
    u16* ao     = (u16*)(ws + alloc((size_t)M_ * NQ_ * 2));
    u16* ckv    = (u16*)(ws + alloc((size_t)M_ * RK_ * 2));
    u16* kropeb = (u16*)(ws + alloc((size_t)M_ * RD_ * 2));
    char* scratch = ws + alloc((size_t)M_ * NUP_ * 4);   // 83.9 MB union region
    float* q_all  = (float*)(scratch);                        // M x 3072 fp32 (dead after build_q)
    float* kv_lat = (float*)(scratch + (size_t)M_ * NQ_ * 4); // M x 640 fp32
    float* up     = (float*)(scratch);                        // M x 5120 fp32 (dead after build_kvt)
    // attn partials alias scratch (q_all/kv_lat/up all consumed before attn):
    size_t poSz = (size_t)512 * 128 * 192 * 2;                // 25.2 MB each
    u16*   po0 = (u16*)(scratch);
    u16*   po1 = (u16*)(scratch + poSz);
    float* pm0 = (float*)(scratch + 2 * poSz);
    float* pl0 = (float*)(scratch + 2 * poSz + 512 * 128 * 4);
    float* pm1 = (float*)(scratch + 2 * poSz + 2 * 512 * 128 * 4);
    float* pl1 = (float*)(scratch + 2 * poSz + 3 * 512 * 128 * 4);

    dim3 tb(32, 8);
    int n4 = M_ * E_ / 4;
    convert_bf16<<<(n4 + 255) / 256, 256, 0, stream>>>(x, xb, n4);
    transpose_w<<<dim3(NQ_ / 32, E_ / 32), tb, 0, stream>>>(wq, wqT, E_, NQ_, NQ_);
    transpose_w<<<dim3(NKVP_ / 32, E_ / 32), tb, 0, stream>>>(wkv, wkvT, E_, NKV_, NKVP_);
    transpose_w<<<dim3(NUP_ / 32, RK_ / 32), tb, 0, stream>>>(wup, wupT, RK_, NUP_, NUP_);
    transpose_w<<<dim3(E_ / 32, NQ_ / 32), tb, 0, stream>>>(wout, woutT, NQ_, E_, E_);

    gemm_bt<<<dim3(NQ_ / 128, M_ / 128), 256, 0, stream>>>(xb, wqT, q_all, M_, NQ_, E_);
    gemm_bt<<<dim3(NKVP_ / 128, M_ / 128), 256, 0, stream>>>(xb, wkvT, kv_lat, M_, NKVP_, E_);

    int nq = M_ * H_ * 96;
    build_q<<<(nq + 255) / 256, 256, 0, stream>>>(q_all, cosT, sinT, qb);
    int nc = M_ * 288;
    build_ckv<<<(nc + 255) / 256, 256, 0, stream>>>(kv_lat, cosT, sinT, ckv, kropeb);

    gemm_bt<<<dim3(NUP_ / 128, M_ / 128), 256, 0, stream>>>(ckv, wupT, up, M_, NUP_, RK_);
    build_kvt<<<B_ * H_ * 32, 256, 0, stream>>>(up, kropeb, kb, vtb);

    attn<<<512, 256, 0, stream>>>(qb, kb, vtb, po0, po1, pm0, pl0, pm1, pl1);
    attn_merge<<<(512 * 128 * 48) / 256, 256, 0, stream>>>(po0, po1, pm0, pl0, pm1, pl1, ao);

    gemm_bt<<<dim3(E_ / 128, M_ / 128), 256, 0, stream>>>(ao, woutT, out, M_, E_, NQ_);
}

// Round 4
// 614.454 us; speedup vs baseline: 1.1580x; 1.1242x over previous
//
#include <hip/hip_runtime.h>
#include <stdint.h>

#define H_ 16
#define DH_ 128
#define RK_ 512
#define RD_ 64
#define B_ 2
#define L_ 2048
#define E_ 2048
#define DQ_ 192            // DH+RD
#define NQ_ (H_*DQ_)       // 3072
#define NKV_ 576
#define NKVP_ 640
#define NUP_ (H_*(2*DH_+RD_)) // 5120
#define M_ (B_*L_)         // 4096

typedef unsigned short u16;
typedef __bf16 bf16x8 __attribute__((ext_vector_type(8)));
typedef float floatx4 __attribute__((ext_vector_type(4)));

__device__ __forceinline__ u16 f2bf(float f) {
    union { float f; uint32_t u; } v; v.f = f;
    uint32_t u = v.u;
    u = (u + 0x7fffu + ((u >> 16) & 1u)) >> 16;
    return (u16)u;
}
__device__ __forceinline__ float bf2f(u16 b) {
    union { uint32_t u; float f; } v; v.u = ((uint32_t)b) << 16; return v.f;
}

__device__ __forceinline__ void gld_lds16(const void* g, void* l) {
    __builtin_amdgcn_global_load_lds((__attribute__((address_space(1))) void*)(g),
                                     (__attribute__((address_space(3))) void*)(l),
                                     16, 0, 0);
}

// ---------------- fp32 -> bf16 elementwise (x) ----------------
__global__ void convert_bf16(const float* __restrict__ in, u16* __restrict__ out, int n4) {
    int i = blockIdx.x * blockDim.x + threadIdx.x;
    if (i >= n4) return;
    float4 v = ((const float4*)in)[i];
    uint2 o;
    o.x = (uint32_t)f2bf(v.x) | ((uint32_t)f2bf(v.y) << 16);
    o.y = (uint32_t)f2bf(v.z) | ((uint32_t)f2bf(v.w) << 16);
    ((uint2*)out)[i] = o;
}

// ---------------- W (KxN fp32) -> Wt (Npad x K bf16), zero pad ----------------
__global__ void transpose_w(const float* __restrict__ W, u16* __restrict__ Wt,
                            int K, int N, int Npad) {
    __shared__ float tile[32][33];
    int n0 = blockIdx.x * 32, k0 = blockIdx.y * 32;
    int tx = threadIdx.x, ty = threadIdx.y; // 32 x 8
    for (int i = 0; i < 4; i++) {
        int k = k0 + ty + i * 8, n = n0 + tx;
        tile[ty + i * 8][tx] = (n < N) ? W[(size_t)k * N + n] : 0.f;
    }
    __syncthreads();
    for (int i = 0; i < 4; i++) {
        int n = n0 + ty + i * 8, k = k0 + tx;
        Wt[(size_t)n * K + k] = f2bf(tile[tx][ty + i * 8]);
    }
}

// ---------------- GEMM: C(MxN fp32) = A(MxK bf16) * Bt(NxK bf16)^T ----------------
__global__ __launch_bounds__(256) void gemm_bt(const u16* __restrict__ A,
                                               const u16* __restrict__ Bt,
                                               float* __restrict__ C,
                                               int M, int N, int K) {
    __shared__ __align__(16) u16 As[128 * 32];
    __shared__ __align__(16) u16 Bs[128 * 32];
    const int tid = threadIdx.x;
    const int wave = tid >> 6, lane = tid & 63;
    const int quad = lane >> 4, l16 = lane & 15;
    const int m0 = blockIdx.y * 128, n0 = blockIdx.x * 128;
    const int wm = (wave >> 1) * 64, wn = (wave & 1) * 64;

    floatx4 zero4 = {0.f, 0.f, 0.f, 0.f};
    floatx4 acc[4][4];
    for (int i = 0; i < 4; i++) for (int j = 0; j < 4; j++) acc[i][j] = zero4;

    const u16* Ab = A + (size_t)m0 * K;
    const u16* Bb = Bt + (size_t)n0 * K;

    for (int k0 = 0; k0 < K; k0 += 32) {
        for (int it = 0; it < 2; ++it) {
            int c = it * 256 + tid;
            int row = c >> 2, cr = c & 3;
            gld_lds16(Ab + (size_t)row * K + k0 + cr * 8, As + c * 8);
            gld_lds16(Bb + (size_t)row * K + k0 + cr * 8, Bs + c * 8);
        }
        __syncthreads();
        bf16x8 af[4], bfr[4];
        for (int i = 0; i < 4; i++) af[i]  = *(const bf16x8*)(As + (wm + i * 16 + l16) * 32 + quad * 8);
        for (int j = 0; j < 4; j++) bfr[j] = *(const bf16x8*)(Bs + (wn + j * 16 + l16) * 32 + quad * 8);
        for (int i = 0; i < 4; i++)
            for (int j = 0; j < 4; j++)
                acc[i][j] = __builtin_amdgcn_mfma_f32_16x16x32_bf16(af[i], bfr[j], acc[i][j], 0, 0, 0);
        __syncthreads();
    }
    for (int i = 0; i < 4; i++)
        for (int j = 0; j < 4; j++) {
            int mrow = m0 + wm + i * 16 + quad * 4;
            int ncol = n0 + wn + j * 16 + l16;
            float* Cp = C + (size_t)mrow * N + ncol;
            for (int r = 0; r < 4; r++) Cp[(size_t)r * N] = acc[i][j][r];
        }
}

// ---------------- build q: rope + scale*log2e + layout (B,H,L,192) bf16 ----------------
__global__ void build_q(const float* __restrict__ q_all, const float* __restrict__ cosT,
                        const float* __restrict__ sinT, u16* __restrict__ qb) {
    const float QS = 0.07216878364870323f * 1.4426950408889634f; // 1/sqrt(192) * log2(e)
    int idx = blockIdx.x * blockDim.x + threadIdx.x;
    if (idx >= M_ * H_ * 96) return;
    int p = idx % 96; int t = idx / 96; int h = t % H_; int row = t / H_;
    int l = row & (L_ - 1); int b = row >> 11;
    const float* src = q_all + (size_t)row * NQ_ + h * DQ_;
    u16* dst = qb + ((size_t)(b * H_ + h) * L_ + l) * DQ_;
    int d = 2 * p;
    float x1 = src[d], x2 = src[d + 1];
    if (d < DH_) { dst[d] = f2bf(x1 * QS); dst[d + 1] = f2bf(x2 * QS); }
    else {
        int i = (d - DH_) >> 1;
        float c = cosT[(size_t)l * 32 + i], s = sinT[(size_t)l * 32 + i];
        dst[d]     = f2bf((x1 * c - x2 * s) * QS);
        dst[d + 1] = f2bf((x1 * s + x2 * c) * QS);
    }
}

// ---------------- build c_kv (bf16) + roped k_rope (bf16) ----------------
__global__ void build_ckv(const float* __restrict__ kv, const float* __restrict__ cosT,
                          const float* __restrict__ sinT, u16* __restrict__ ckv,
                          u16* __restrict__ kropeb) {
    int idx = blockIdx.x * blockDim.x + threadIdx.x;
    if (idx >= M_ * 288) return;
    int j = idx % 288; int row = idx / 288;
    int l = row & (L_ - 1);
    const float* src = kv + (size_t)row * NKVP_;
    if (j < 256) {
        ckv[(size_t)row * RK_ + 2 * j]     = f2bf(src[2 * j]);
        ckv[(size_t)row * RK_ + 2 * j + 1] = f2bf(src[2 * j + 1]);
    } else {
        int i = j - 256;
        float x1 = src[RK_ + 2 * i], x2 = src[RK_ + 2 * i + 1];
        float c = cosT[(size_t)l * 32 + i], s = sinT[(size_t)l * 32 + i];
        kropeb[(size_t)row * RD_ + 2 * i]     = f2bf(x1 * c - x2 * s);
        kropeb[(size_t)row * RD_ + 2 * i + 1] = f2bf(x1 * s + x2 * c);
    }
}

// ---------------- build k (B,H,L,192) + vT (B,H,192,L perm) bf16 ----------------
// vtb stores s-index permuted within each 32-group: k = ((s>>2)&3)*8 + ((s>>4)&1)*4 + (s&3)
// so the PV MFMA's B-frag element (k=quad*8+j) matches the S^T C-layout rows.
__global__ __launch_bounds__(256) void build_kvt(const float* __restrict__ up,
        const u16* __restrict__ kropeb, u16* __restrict__ kb, u16* __restrict__ vtb) {
    __shared__ float vt[64][193];
    int blk = blockIdx.x;          // (b*H+h)*32 + lt
    int lt = blk & 31; int bh = blk >> 5; int h = bh % H_; int b = bh / H_;
    int tid = threadIdx.x;
    int l0 = lt * 64;
    for (int it = 0; it < 48; ++it) {
        int idx = it * 256 + tid;  // 64*192
        int lr = idx / 192, d = idx % 192;
        size_t row = (size_t)b * L_ + l0 + lr;
        float vv = (d < DH_) ? up[row * NUP_ + h * 320 + DH_ + d]
                             : up[row * NUP_ + h * 320 + 2 * DH_ + (d - DH_)];
        vt[lr][d] = vv;
        u16 kbf = (d < DH_) ? f2bf(up[row * NUP_ + h * 320 + d])
                            : kropeb[row * RD_ + (d - DH_)];
        kb[((size_t)bh * L_ + l0 + lr) * DQ_ + d] = kbf;
    }
    __syncthreads();
    for (int it = 0; it < 48; ++it) {
        int idx = it * 256 + tid;
        int lr = idx & 63, d = idx >> 6;
        int l = l0 + lr;
        int s5 = l & 31;
        int k5 = ((s5 >> 2) & 3) * 8 + ((s5 >> 4) & 1) * 4 + (s5 & 3);
        int lp = (l & ~31) | k5;
        vtb[((size_t)bh * DQ_ + d) * L_ + lp] = f2bf(vt[lr][d]);
    }
}

// ---------------- flash attention, causal, S^T, 512-thread blocks ----------------
// Grid = 256 blocks exactly (1 per CU). Block (bh, t, j): supertile QT=7-t then
// QT=t (256 q-rows each), split-s half j -> every block exactly 18 st-iters.
// Wave w owns q rows {a*128 + w*16 + l16 : a in 0,1}. Partials to po/pm/pl,
// merged by attn_merge. All stile loops compile-time-bounded (no scratch).
__global__ __launch_bounds__(512, 2) void attn(const u16* __restrict__ qb,
        const u16* __restrict__ kb, const u16* __restrict__ vtb,
        u16* __restrict__ po0, u16* __restrict__ po1,
        float* __restrict__ pm0, float* __restrict__ pl0,
        float* __restrict__ pm1, float* __restrict__ pl1) {
    __shared__ __align__(16) u16 Ks[6 * 64 * 32];
    __shared__ __align__(16) u16 Vs[2 * 192 * 32];
    int id = blockIdx.x;
    int bh = id & 31, tj = id >> 5;      // same-bh blocks share XCD (id%8 = bh%8)
    int t = tj >> 1, j = tj & 1;
    int tid = threadIdx.x, wave = tid >> 6, lane = tid & 63;
    int quad = lane >> 4, l16 = lane & 15;

    u16* po = j ? po1 : po0;
    float* pm = j ? pm1 : pm0;
    float* pl = j ? pl1 : pl0;

    const u16* kbase0 = kb + (size_t)bh * L_ * DQ_;
    const u16* vbase0 = vtb + (size_t)bh * (size_t)DQ_ * L_;
    floatx4 zero4 = {0.f, 0.f, 0.f, 0.f};

    for (int seg = 0; seg < 2; ++seg) {
        const int QT = seg == 0 ? (7 - t) : t;
        const int st0 = j ? (2 * QT + 2) : 0;
        const int st1 = j ? (4 * QT + 3) : (2 * QT + 1);

        bf16x8 aq[2][6];
        const u16* qbase = qb + ((size_t)bh * L_ + QT * 256 + wave * 16 + l16) * DQ_;
        for (int a = 0; a < 2; a++)
            for (int kk = 0; kk < 6; kk++)
                aq[a][kk] = *(const bf16x8*)(qbase + a * 128 * DQ_ + kk * 32 + quad * 8);

        floatx4 o[2][12];
        for (int a = 0; a < 2; a++) for (int i = 0; i < 12; i++) o[a][i] = zero4;
        float m_i[2] = {-INFINITY, -INFINITY};
        float l_i[2] = {0.f, 0.f};

        for (int st = st0; st <= st1; ++st) {
            // stage K: Ks[kk6][64][32], 3 lds-dma instrs per thread
            const u16* kg = kbase0 + (size_t)st * 64 * DQ_;
            for (int it = 0; it < 3; ++it) {
                int c = it * 512 + tid;
                int kk = c >> 8, cc = c & 255;
                int s = cc >> 2, q4 = cc & 3;
                gld_lds16(kg + (size_t)s * DQ_ + kk * 32 + q4 * 8, Ks + c * 8);
            }
            // stage V: Vs[g2][192][32]
            const u16* vg = vbase0 + st * 64;
            for (int it = 0; it < 3; ++it) {
                int c = it * 512 + tid;
                int g = (c >= 768) ? 1 : 0;
                int cc = c - g * 768;
                int d = cc >> 2, q4 = cc & 3;
                gld_lds16(vg + (size_t)d * L_ + g * 32 + q4 * 8, Vs + c * 8);
            }
            __syncthreads();

            // liveness: R multiple of 16; rowset live iff R >= 0
            int R0 = QT * 256 + wave * 16 - st * 64;
            int R1 = R0 + 128;
            int smax0 = min(3, (R0 + 15) >> 4);
            int smax1 = min(3, (R1 + 15) >> 4);
            bool live0 = smax0 >= 0, live1 = smax1 >= 0;

            float pv[2][4][4];
            float mxa[2] = {-INFINITY, -INFINITY};
#pragma unroll
            for (int stile = 0; stile < 4; ++stile) {
                if (stile > smax1) {
                    for (int r = 0; r < 4; r++) { pv[0][stile][r] = 0.f; pv[1][stile][r] = 0.f; }
                    continue;
                }
                bool do0 = (stile <= smax0);
                floatx4 s1v = zero4, s0v = zero4;
                for (int kk = 0; kk < 6; kk++) {
                    bf16x8 kf = *(const bf16x8*)(Ks + kk * 2048 + (stile * 16 + l16) * 32 + quad * 8);
                    s1v = __builtin_amdgcn_mfma_f32_16x16x32_bf16(kf, aq[1][kk], s1v, 0, 0, 0);
                    if (do0) s0v = __builtin_amdgcn_mfma_f32_16x16x32_bf16(kf, aq[0][kk], s0v, 0, 0, 0);
                }
                int sb = stile * 16;
                if (sb + 15 > R1) {
                    for (int r = 0; r < 4; r++) {
                        float v = (sb + quad * 4 + r > R1 + l16) ? -1e30f : s1v[r];
                        pv[1][stile][r] = v; mxa[1] = fmaxf(mxa[1], v);
                    }
                } else {
                    for (int r = 0; r < 4; r++) { pv[1][stile][r] = s1v[r]; mxa[1] = fmaxf(mxa[1], s1v[r]); }
                }
                if (do0) {
                    if (sb + 15 > R0) {
                        for (int r = 0; r < 4; r++) {
                            float v = (sb + quad * 4 + r > R0 + l16) ? -1e30f : s0v[r];
                            pv[0][stile][r] = v; mxa[0] = fmaxf(mxa[0], v);
                        }
                    } else {
                        for (int r = 0; r < 4; r++) { pv[0][stile][r] = s0v[r]; mxa[0] = fmaxf(mxa[0], s0v[r]); }
                    }
                } else {
                    for (int r = 0; r < 4; r++) pv[0][stile][r] = 0.f;
                }
            }

            bf16x8 pf[2][2];
            bool lv[2] = {live0, live1};
            int smx[2] = {smax0, smax1};
#pragma unroll
            for (int a = 0; a < 2; a++) {
                if (!lv[a]) continue;
                float mx = mxa[a];
                mx = fmaxf(mx, __shfl_xor(mx, 16));
                mx = fmaxf(mx, __shfl_xor(mx, 32));
                float mn = fmaxf(m_i[a], mx);
                float alpha = exp2f(m_i[a] - mn);
                m_i[a] = mn;
                float rs = 0.f;
#pragma unroll
                for (int stile = 0; stile < 4; ++stile) {
                    if (stile > smx[a]) continue;
                    for (int r = 0; r < 4; r++) {
                        float e = exp2f(pv[a][stile][r] - mn);
                        pv[a][stile][r] = e;
                        rs += e;
                    }
                }
                rs += __shfl_xor(rs, 16);
                rs += __shfl_xor(rs, 32);
                l_i[a] = l_i[a] * alpha + rs;
                if (__any(alpha != 1.0f))
                    for (int i = 0; i < 12; i++) o[a][i] *= alpha;
                for (int g = 0; g < 2; g++) {
                    union { bf16x8 v; u16 s[8]; } u;
                    for (int r = 0; r < 4; r++) {
                        u.s[r]     = f2bf(pv[a][g * 2][r]);
                        u.s[4 + r] = f2bf(pv[a][g * 2 + 1][r]);
                    }
                    pf[a][g] = u.v;
                }
            }

            for (int g = 0; g < 2; g++)
                for (int dtile = 0; dtile < 12; dtile++) {
                    bf16x8 vf = *(const bf16x8*)(Vs + g * 6144 + (dtile * 16 + l16) * 32 + quad * 8);
                    if (live0)
                        o[0][dtile] = __builtin_amdgcn_mfma_f32_16x16x32_bf16(vf, pf[0][g], o[0][dtile], 0, 0, 0);
                    if (live1)
                        o[1][dtile] = __builtin_amdgcn_mfma_f32_16x16x32_bf16(vf, pf[1][g], o[1][dtile], 0, 0, 0);
                }
            __syncthreads();
        }

        // write partials: po[tile][q 256][d 192] bf16, pm/pl[tile][q 256]
        int tile = bh * 8 + QT;
        for (int a = 0; a < 2; a++) {
            int q = a * 128 + wave * 16 + l16;
            u16* dst = po + ((size_t)tile * 256 + q) * 192;
            for (int dtile = 0; dtile < 12; dtile++) {
                ushort4 pk;
                pk.x = f2bf(o[a][dtile][0]);
                pk.y = f2bf(o[a][dtile][1]);
                pk.z = f2bf(o[a][dtile][2]);
                pk.w = f2bf(o[a][dtile][3]);
                *(ushort4*)(dst + dtile * 16 + quad * 4) = pk;
            }
            if (quad == 0) {
                pm[(size_t)tile * 256 + q] = m_i[a];
                pl[(size_t)tile * 256 + q] = l_i[a];
            }
        }
        __syncthreads();
    }
}

// ---------------- merge the two split-s halves -> ao (B,L,H,192) bf16 ----------------
__global__ void attn_merge(const u16* __restrict__ po0, const u16* __restrict__ po1,
                           const float* __restrict__ pm0, const float* __restrict__ pl0,
                           const float* __restrict__ pm1, const float* __restrict__ pl1,
                           u16* __restrict__ ao) {
    int idx = blockIdx.x * blockDim.x + threadIdx.x;   // 256*256*48
    int c = idx % 48; int rest = idx / 48;
    int q = rest & 255; int tile = rest >> 8;
    int bh = tile >> 3, QT = tile & 7;
    size_t mi = (size_t)tile * 256 + q;
    float m0 = pm0[mi], m1 = pm1[mi];
    float l0 = pl0[mi], l1 = pl1[mi];
    float m = fmaxf(m0, m1);
    float a0 = exp2f(m0 - m), a1 = exp2f(m1 - m);
    float inv = 1.0f / (l0 * a0 + l1 * a1);
    float s0 = a0 * inv, s1 = a1 * inv;
    ushort4 u0 = *(const ushort4*)(po0 + mi * 192 + c * 4);
    ushort4 u1 = *(const ushort4*)(po1 + mi * 192 + c * 4);
    int b = bh >> 4, h = bh & 15;
    int l = QT * 256 + q;
    u16* dst = ao + (((size_t)(b * L_ + l)) * H_ + h) * DQ_ + c * 4;
    ushort4 pk;
    pk.x = f2bf(bf2f(u0.x) * s0 + bf2f(u1.x) * s1);
    pk.y = f2bf(bf2f(u0.y) * s0 + bf2f(u1.y) * s1);
    pk.z = f2bf(bf2f(u0.z) * s0 + bf2f(u1.z) * s1);
    pk.w = f2bf(bf2f(u0.w) * s0 + bf2f(u1.w) * s1);
    *(ushort4*)dst = pk;
}

extern "C" void kernel_launch(void* const* d_in, const int* in_sizes, int n_in,
                              void* d_out, int out_size, void* d_ws, size_t ws_size,
                              hipStream_t stream) {
    const float* x    = (const float*)d_in[0];
    const float* cosT = (const float*)d_in[1];
    const float* sinT = (const float*)d_in[2];
    const float* wq   = (const float*)d_in[3];
    const float* wkv  = (const float*)d_in[4];
    const float* wup  = (const float*)d_in[5];
    const float* wout = (const float*)d_in[6];
    float* out = (float*)d_out;
    char* ws = (char*)d_ws;

    size_t off = 0;
    auto alloc = [&](size_t b) { size_t r = off; off += (b + 255) & ~(size_t)255; return r; };
    u16* xb     = (u16*)(ws + alloc((size_t)M_ * E_ * 2));
    u16* wqT    = (u16*)(ws + alloc((size_t)NQ_ * E_ * 2));
    u16* wkvT   = (u16*)(ws + alloc((size_t)NKVP_ * E_ * 2));
    u16* wupT   = (u16*)(ws + alloc((size_t)NUP_ * RK_ * 2));
    u16* woutT  = (u16*)(ws + alloc((size_t)E_ * NQ_ * 2));
    u16* qb     = (u16*)(ws + alloc((size_t)B_ * H_ * L_ * DQ_ * 2));
    u16* kb     = (u16*)(ws + alloc((size_t)B_ * H_ * L_ * DQ_ * 2));
    u16* vtb    = (u16*)(ws + alloc((size_t)B_ * H_ * DQ_ * L_ * 2));
    u16* ao     = (u16*)(ws + alloc((size_t)M_ * NQ_ * 2));
    u16* ckv    = (u16*)(ws + alloc((size_t)M_ * RK_ * 2));
    u16* kropeb = (u16*)(ws + alloc((size_t)M_ * RD_ * 2));
    char* scratch = ws + alloc((size_t)M_ * NUP_ * 4);   // 83.9 MB union region
    float* q_all  = (float*)(scratch);                        // M x 3072 fp32 (dead after build_q)
    float* kv_lat = (float*)(scratch + (size_t)M_ * NQ_ * 4); // M x 640 fp32
    float* up     = (float*)(scratch);                        // M x 5120 fp32 (dead after build_kvt)
    // attn partials alias scratch (q_all/kv_lat/up all consumed before attn):
    size_t poSz = (size_t)256 * 256 * 192 * 2;                // 25.2 MB each
    u16*   po0 = (u16*)(scratch);
    u16*   po1 = (u16*)(scratch + poSz);
    float* pm0 = (float*)(scratch + 2 * poSz);
    float* pl0 = (float*)(scratch + 2 * poSz + 256 * 256 * 4);
    float* pm1 = (float*)(scratch + 2 * poSz + 2 * 256 * 256 * 4);
    float* pl1 = (float*)(scratch + 2 * poSz + 3 * 256 * 256 * 4);

    dim3 tb(32, 8);
    int n4 = M_ * E_ / 4;
    convert_bf16<<<(n4 + 255) / 256, 256, 0, stream>>>(x, xb, n4);
    transpose_w<<<dim3(NQ_ / 32, E_ / 32), tb, 0, stream>>>(wq, wqT, E_, NQ_, NQ_);
    transpose_w<<<dim3(NKVP_ / 32, E_ / 32), tb, 0, stream>>>(wkv, wkvT, E_, NKV_, NKVP_);
    transpose_w<<<dim3(NUP_ / 32, RK_ / 32), tb, 0, stream>>>(wup, wupT, RK_, NUP_, NUP_);
    transpose_w<<<dim3(E_ / 32, NQ_ / 32), tb, 0, stream>>>(wout, woutT, NQ_, E_, E_);

    gemm_bt<<<dim3(NQ_ / 128, M_ / 128), 256, 0, stream>>>(xb, wqT, q_all, M_, NQ_, E_);
    gemm_bt<<<dim3(NKVP_ / 128, M_ / 128), 256, 0, stream>>>(xb, wkvT, kv_lat, M_, NKVP_, E_);

    int nq = M_ * H_ * 96;
    build_q<<<(nq + 255) / 256, 256, 0, stream>>>(q_all, cosT, sinT, qb);
    int nc = M_ * 288;
    build_ckv<<<(nc + 255) / 256, 256, 0, stream>>>(kv_lat, cosT, sinT, ckv, kropeb);

    gemm_bt<<<dim3(NUP_ / 128, M_ / 128), 256, 0, stream>>>(ckv, wupT, up, M_, NUP_, RK_);
    build_kvt<<<B_ * H_ * 32, 256, 0, stream>>>(up, kropeb, kb, vtb);

    attn<<<256, 512, 0, stream>>>(qb, kb, vtb, po0, po1, pm0, pl0, pm1, pl1);
    attn_merge<<<(256 * 256 * 48) / 256, 256, 0, stream>>>(po0, po1, pm0, pl0, pm1, pl1, ao);

    gemm_bt<<<dim3(E_ / 128, M_ / 128), 256, 0, stream>>>(ao, woutT, out, M_, E_, NQ_);
}